// Round 4
// baseline (630.276 us; speedup 1.0000x reference)
//
#include <hip/hip_runtime.h>

typedef unsigned short u16;
typedef unsigned int u32;
typedef unsigned long long u64;
typedef __attribute__((ext_vector_type(8))) short bf16x8;
typedef __attribute__((ext_vector_type(4))) float f32x4;

#define NB 2
#define NS 2048
#define NDM 1024
#define NH 16

__device__ __forceinline__ u16 f2bf(float f) {
  union { float f; unsigned u; } v; v.f = f;
  return (u16)((v.u + 0x7fffu + ((v.u >> 16) & 1u)) >> 16);
}

__global__ __launch_bounds__(256) void cast_bf16(const float* __restrict__ in,
                                                 u16* __restrict__ out, int n4) {
  int i = blockIdx.x * 256 + threadIdx.x;
  if (i < n4) {
    const float4 v = reinterpret_cast<const float4*>(in)[i];
    ushort4 o; o.x = f2bf(v.x); o.y = f2bf(v.y); o.z = f2bf(v.z); o.w = f2bf(v.w);
    reinterpret_cast<ushort4*>(out)[i] = o;
  }
}

// in: f32 [1024][1024] row-major -> out: bf16 [1024][1024] = in^T
__global__ __launch_bounds__(256) void transpose_w(const float* __restrict__ in,
                                                   u16* __restrict__ out) {
  __shared__ float tile[32][33];
  int bx = blockIdx.x, by = blockIdx.y;
  int x = threadIdx.x & 31, y0 = threadIdx.x >> 5;
#pragma unroll
  for (int i = 0; i < 4; i++) {
    int y = y0 + i * 8;
    tile[y][x] = in[(by * 32 + y) * NDM + bx * 32 + x];
  }
  __syncthreads();
#pragma unroll
  for (int i = 0; i < 4; i++) {
    int y = y0 + i * 8;
    out[(bx * 32 + y) * NDM + by * 32 + x] = f2bf(tile[x][y]);
  }
}

// ---- mask [B,S,S] -> bitmask, 1 bit/col ----
__global__ __launch_bounds__(256) void mask2bits(const u32* __restrict__ mask, u32* __restrict__ mb) {
  int idx = blockIdx.x * 256 + threadIdx.x;
  u32 mw0 = mask[threadIdx.x & 63];
  bool floatmode = (__ballot(mw0 == 0x3F800000u) != 0ull);
  bool bytemode = !floatmode && (__ballot((mw0 >> 8) != 0u) != 0ull);
  int row = idx >> 6;
  int wword = idx & 63;
  u32 bits = 0;
  if (!bytemode) {
    const uint4* p = reinterpret_cast<const uint4*>(mask + (size_t)row * 2048 + wword * 32);
#pragma unroll
    for (int i = 0; i < 8; i++) {
      uint4 v = p[i];
      bits |= (v.x ? 1u : 0u) << (i * 4 + 0);
      bits |= (v.y ? 1u : 0u) << (i * 4 + 1);
      bits |= (v.z ? 1u : 0u) << (i * 4 + 2);
      bits |= (v.w ? 1u : 0u) << (i * 4 + 3);
    }
  } else {
    const uint4* p = reinterpret_cast<const uint4*>(
        reinterpret_cast<const unsigned char*>(mask) + (size_t)row * 2048 + wword * 32);
#pragma unroll
    for (int i = 0; i < 2; i++) {
      uint4 v = p[i];
      u32 wsv[4] = {v.x, v.y, v.z, v.w};
#pragma unroll
      for (int j = 0; j < 4; j++)
#pragma unroll
        for (int kq = 0; kq < 4; kq++)
          bits |= ((((wsv[j] >> (kq * 8)) & 0xffu) != 0u) ? 1u : 0u) << (i * 16 + j * 4 + kq);
    }
  }
  mb[idx] = bits;
}

// ---- 128x128-tile bf16 GEMM, B^T layout ----
struct GArgs { const u16* X; const u16* W; const float* bias; void* out; int mode; float scale; };

__global__ __launch_bounds__(256, 2) void gemm_bt(GArgs g0, GArgs g1, GArgs g2) {
  GArgs ga = (blockIdx.z == 0) ? g0 : (blockIdx.z == 1 ? g1 : g2);
  const int K = 1024, N = 1024;
  __shared__ u16 As[128 * 32];
  __shared__ u16 Bs[128 * 32];
  const int t = threadIdx.x, w = t >> 6, l = t & 63;
  const int m0 = blockIdx.x * 128, n0 = blockIdx.y * 128;
  const int wm = (w >> 1) * 64, wn = (w & 1) * 64;
  const f32x4 fz = {0.f, 0.f, 0.f, 0.f};
  f32x4 acc[4][4];
#pragma unroll
  for (int i = 0; i < 4; i++)
#pragma unroll
    for (int j = 0; j < 4; j++) acc[i][j] = fz;

  for (int k0 = 0; k0 < K; k0 += 32) {
#pragma unroll
    for (int i = 0; i < 2; i++) {
      int idx = i * 256 + w * 64 + l;
      int r = idx >> 2, c = (idx & 3) * 8;
      __builtin_amdgcn_global_load_lds(
          reinterpret_cast<const unsigned*>(ga.X + (size_t)(m0 + r) * K + k0 + c),
          reinterpret_cast<unsigned*>(&As[(i * 256 + w * 64) * 8]), 16, 0, 0);
      __builtin_amdgcn_global_load_lds(
          reinterpret_cast<const unsigned*>(ga.W + (size_t)(n0 + r) * K + k0 + c),
          reinterpret_cast<unsigned*>(&Bs[(i * 256 + w * 64) * 8]), 16, 0, 0);
    }
    __syncthreads();
    bf16x8 af[4], bfr[4];
#pragma unroll
    for (int mt = 0; mt < 4; mt++)
      af[mt] = *reinterpret_cast<const bf16x8*>(&As[(wm + mt * 16 + (l & 15)) * 32 + (l >> 4) * 8]);
#pragma unroll
    for (int nt = 0; nt < 4; nt++)
      bfr[nt] = *reinterpret_cast<const bf16x8*>(&Bs[(wn + nt * 16 + (l & 15)) * 32 + (l >> 4) * 8]);
#pragma unroll
    for (int mt = 0; mt < 4; mt++)
#pragma unroll
      for (int nt = 0; nt < 4; nt++)
        acc[mt][nt] = __builtin_amdgcn_mfma_f32_16x16x32_bf16(af[mt], bfr[nt], acc[mt][nt], 0, 0, 0);
    __syncthreads();
  }

#pragma unroll
  for (int nt = 0; nt < 4; nt++) {
    int n = n0 + wn + nt * 16 + (l & 15);
    float bias = ga.bias[n];
#pragma unroll
    for (int mt = 0; mt < 4; mt++) {
      int mb = m0 + wm + mt * 16 + ((l >> 4) << 2);
#pragma unroll
      for (int r = 0; r < 4; r++) {
        int m = mb + r;
        float v = (acc[mt][nt][r] + bias) * ga.scale;
        if (ga.mode == 2) {
          reinterpret_cast<float*>(ga.out)[(size_t)m * N + n] = v;
        } else {
          int b = m >> 11, s = m & 2047, h = n >> 6, d = n & 63;
          if (ga.mode == 0)
            reinterpret_cast<u16*>(ga.out)[(((size_t)(b * NH + h) * NS + s) << 6) + d] = f2bf(v);
          else
            reinterpret_cast<u16*>(ga.out)[((size_t)(b * NH + h) * 64 + d) * NS + s] = f2bf(v);
        }
      }
    }
  }
}

// ---- attention: barrier-free, 2 independent waves/block, 2048 blocks for occupancy ----
__global__ __launch_bounds__(128, 5) void attn_kernel(
    const u16* __restrict__ qh, const u16* __restrict__ kh, const u16* __restrict__ vT,
    const u64* __restrict__ mb64, float* __restrict__ attn, u16* __restrict__ ctx) {
  __shared__ u16 Ps[2][16 * 72];      // per-wave bf16 P tile (PV A-frag relayout)
  __shared__ float Pf[2][16 * 68];    // per-wave f32 P tile (full-line attn stores)
  const int t = threadIdx.x, w = t >> 6, l = t & 63;
  int id = blockIdx.x;                       // 2048 blocks
  int wgid = (id & 7) * 256 + (id >> 3);     // XCD-chunked bijective swizzle (2048 % 8 == 0)
  int qt = wgid & 63, pr = wgid >> 6;        // 64 q-tiles of 32 rows per (b,h)
  int h = pr & 15, b = pr >> 4;
  const size_t head = (size_t)b * NH + h;
  const u16* qp = qh + head * NS * 64;
  const u16* kp = kh + head * NS * 64;
  const u16* vp = vT + head * 64 * NS;
  const int qr0 = qt * 32 + w * 16;
  const int lo = l & 15, hi = l >> 4;
  const int rbase = hi << 2;
  const f32x4 fz = {0.f, 0.f, 0.f, 0.f};

  bf16x8 aq0, aq1;
  {
    const u16* p = qp + (size_t)(qr0 + lo) * 64 + hi * 8;
    aq0 = *reinterpret_cast<const bf16x8*>(p);
    aq1 = *reinterpret_cast<const bf16x8*>(p + 32);
  }
  const u64* mrow = mb64 + ((size_t)b * NS + qr0 + rbase) * 32;

  auto loadK = [&](bf16x8* dst, int c) {
    const u16* kb = kp + (size_t)(c * 64) * 64;
#pragma unroll
    for (int ct = 0; ct < 4; ++ct) {
      const u16* p = kb + (size_t)(ct * 16 + lo) * 64 + hi * 8;
      dst[2 * ct] = *reinterpret_cast<const bf16x8*>(p);
      dst[2 * ct + 1] = *reinterpret_cast<const bf16x8*>(p + 32);
    }
  };
  auto qk = [&](const bf16x8* bk, f32x4* s) {
#pragma unroll
    for (int ct = 0; ct < 4; ++ct) {
      f32x4 acc = fz;
      acc = __builtin_amdgcn_mfma_f32_16x16x32_bf16(aq0, bk[2 * ct], acc, 0, 0, 0);
      acc = __builtin_amdgcn_mfma_f32_16x16x32_bf16(aq1, bk[2 * ct + 1], acc, 0, 0, 0);
      s[ct] = acc;
    }
  };

  // ---- pass 1: row sums only (q pre-scaled by 1/8 in projection) ----
  float rs[4] = {0.f, 0.f, 0.f, 0.f};
  {
    bf16x8 bkA[8], bkB[8];
    loadK(bkA, 0);
    for (int c = 0; c < 32; c += 2) {
      loadK(bkB, c + 1);
      {
        u64 mwv[4] = {mrow[c], mrow[32 + c], mrow[64 + c], mrow[96 + c]};
        f32x4 s[4]; qk(bkA, s);
#pragma unroll
        for (int ct = 0; ct < 4; ++ct) {
          int bit = ct * 16 + lo;
#pragma unroll
          for (int r = 0; r < 4; ++r)
            rs[r] += ((mwv[r] >> bit) & 1ull) ? 0.f : __expf(s[ct][r]);
        }
      }
      if (c + 2 < 32) loadK(bkA, c + 2);
      {
        int c1 = c + 1;
        u64 mwv[4] = {mrow[c1], mrow[32 + c1], mrow[64 + c1], mrow[96 + c1]};
        f32x4 s[4]; qk(bkB, s);
#pragma unroll
        for (int ct = 0; ct < 4; ++ct) {
          int bit = ct * 16 + lo;
#pragma unroll
          for (int r = 0; r < 4; ++r)
            rs[r] += ((mwv[r] >> bit) & 1ull) ? 0.f : __expf(s[ct][r]);
        }
      }
    }
  }
#pragma unroll
  for (int r = 0; r < 4; ++r) {
    float v = rs[r];
    v += __shfl_xor(v, 1); v += __shfl_xor(v, 2);
    v += __shfl_xor(v, 4); v += __shfl_xor(v, 8);
    rs[r] = 1.f / fmaxf(v, 1e-30f);
  }

  // ---- pass 2: recompute, full-line nontemporal attn stores via Pf, PV ----
  f32x4 cacc[4];
#pragma unroll
  for (int i = 0; i < 4; i++) cacc[i] = fz;
  u16* psw = &Ps[w][0];
  float* pfw = &Pf[w][0];
  float* abase = attn + (head * NS + qr0) * NS;

  {
    bf16x8 bkA[8], bkB[8];
    loadK(bkA, 0);
    for (int c = 0; c < 32; c += 2) {
      loadK(bkB, c + 1);
#pragma unroll
      for (int half = 0; half < 2; ++half) {
        int cc = c + half;
        const bf16x8* bk = half ? bkB : bkA;
        u64 mwv[4] = {mrow[cc], mrow[32 + cc], mrow[64 + cc], mrow[96 + cc]};
        f32x4 s[4]; qk(bk, s);
        if (half == 0 && c + 2 < 32) loadK(bkA, c + 2);
        // V fragments for this chunk (issue loads before any stores: vmcnt retires in-order)
        bf16x8 bv[8];
        {
          const u16* vb = vp + cc * 64;
#pragma unroll
          for (int ct = 0; ct < 4; ++ct) {
            const u16* p = vb + (size_t)(ct * 16 + lo) * NS + hi * 8;
            bv[2 * ct] = *reinterpret_cast<const bf16x8*>(p);
            bv[2 * ct + 1] = *reinterpret_cast<const bf16x8*>(p + 32);
          }
        }
#pragma unroll
        for (int ct = 0; ct < 4; ++ct) {
          int bit = ct * 16 + lo;
#pragma unroll
          for (int r = 0; r < 4; ++r) {
            float p = ((mwv[r] >> bit) & 1ull) ? 0.f : __expf(s[ct][r]) * rs[r];
            pfw[(rbase + r) * 68 + ct * 16 + lo] = p;
            psw[(rbase + r) * 72 + ct * 16 + lo] = f2bf(p);
          }
        }
        // full-line (1KB/instr) nontemporal attn stores
#pragma unroll
        for (int i2 = 0; i2 < 4; ++i2) {
          int row = i2 * 4 + hi;
          f32x4 pv4 = *reinterpret_cast<const f32x4*>(&pfw[row * 68 + lo * 4]);
          __builtin_nontemporal_store(pv4,
              reinterpret_cast<f32x4*>(abase + (size_t)row * NS + cc * 64 + lo * 4));
        }
        bf16x8 pa0 = *reinterpret_cast<const bf16x8*>(&psw[lo * 72 + hi * 8]);
        bf16x8 pa1 = *reinterpret_cast<const bf16x8*>(&psw[lo * 72 + 32 + hi * 8]);
#pragma unroll
        for (int ct = 0; ct < 4; ++ct) {
          cacc[ct] = __builtin_amdgcn_mfma_f32_16x16x32_bf16(pa0, bv[2 * ct], cacc[ct], 0, 0, 0);
          cacc[ct] = __builtin_amdgcn_mfma_f32_16x16x32_bf16(pa1, bv[2 * ct + 1], cacc[ct], 0, 0, 0);
        }
      }
    }
  }
#pragma unroll
  for (int ct = 0; ct < 4; ++ct)
#pragma unroll
    for (int r = 0; r < 4; ++r) {
      int qr = qr0 + rbase + r;
      int dv = ct * 16 + lo;
      ctx[((size_t)b * NS + qr) * 1024 + h * 64 + dv] = f2bf(cacc[ct][r]);
    }
}

extern "C" void kernel_launch(void* const* d_in, const int* in_sizes, int n_in,
                              void* d_out, int out_size, void* d_ws, size_t ws_size,
                              hipStream_t stream) {
  const float* Q = (const float*)d_in[0];
  const float* K = (const float*)d_in[1];
  const float* V = (const float*)d_in[2];
  const u32* mask = (const u32*)d_in[3];
  const float* wq = (const float*)d_in[4];
  const float* bq = (const float*)d_in[5];
  const float* wk = (const float*)d_in[6];
  const float* bk = (const float*)d_in[7];
  const float* wv = (const float*)d_in[8];
  const float* bv = (const float*)d_in[9];
  const float* wo = (const float*)d_in[10];
  const float* bo = (const float*)d_in[11];
  float* out = (float*)d_out;
  float* attn = out + (size_t)NB * NS * NDM;

  char* ws = (char*)d_ws;
  u16* Qb  = (u16*)(ws + 0);
  u16* Kb  = (u16*)(ws + 8388608);
  u16* Vb  = (u16*)(ws + 16777216);
  u16* wqT = (u16*)(ws + 25165824);
  u16* wkT = (u16*)(ws + 27262976);
  u16* wvT = (u16*)(ws + 29360128);
  u16* woT = (u16*)(ws + 31457280);
  u16* qhd = (u16*)(ws + 33554432);
  u16* khd = (u16*)(ws + 41943040);
  u16* vTd = (u16*)(ws + 50331648);
  u16* ctx = (u16*)(ws + 58720256);
  u32* mbits = (u32*)(ws + 0);

  cast_bf16<<<4096, 256, 0, stream>>>(Q, Qb, 1048576);
  cast_bf16<<<4096, 256, 0, stream>>>(K, Kb, 1048576);
  cast_bf16<<<4096, 256, 0, stream>>>(V, Vb, 1048576);
  transpose_w<<<dim3(32, 32), 256, 0, stream>>>(wq, wqT);
  transpose_w<<<dim3(32, 32), 256, 0, stream>>>(wk, wkT);
  transpose_w<<<dim3(32, 32), 256, 0, stream>>>(wv, wvT);
  transpose_w<<<dim3(32, 32), 256, 0, stream>>>(wo, woT);

  GArgs gq = {Qb, wqT, bq, (void*)qhd, 0, 0.125f};   // fold 1/sqrt(dk) into q
  GArgs gk = {Kb, wkT, bk, (void*)khd, 0, 1.0f};
  GArgs gv = {Vb, wvT, bv, (void*)vTd, 1, 1.0f};
  gemm_bt<<<dim3(32, 8, 3), 256, 0, stream>>>(gq, gk, gv);

  mask2bits<<<1024, 256, 0, stream>>>(mask, mbits);

  attn_kernel<<<2048, 128, 0, stream>>>(qhd, khd, vTd, (const u64*)mbits, attn, ctx);

  GArgs go = {ctx, woT, bo, d_out, 2, 1.0f};
  gemm_bt<<<dim3(32, 8, 1), 256, 0, stream>>>(go, go, go);
}

// Round 5
// 532.631 us; speedup vs baseline: 1.1833x; 1.1833x over previous
//
#include <hip/hip_runtime.h>

typedef unsigned short u16;
typedef unsigned int u32;
typedef unsigned long long u64;
typedef __attribute__((ext_vector_type(8))) short bf16x8;
typedef __attribute__((ext_vector_type(4))) float f32x4;

#define NB 2
#define NS 2048
#define NDM 1024
#define NH 16

__device__ __forceinline__ u16 f2bf(float f) {
  union { float f; unsigned u; } v; v.f = f;
  return (u16)((v.u + 0x7fffu + ((v.u >> 16) & 1u)) >> 16);
}

__global__ __launch_bounds__(256) void cast_bf16(const float* __restrict__ in,
                                                 u16* __restrict__ out, int n4) {
  int i = blockIdx.x * 256 + threadIdx.x;
  if (i < n4) {
    const float4 v = reinterpret_cast<const float4*>(in)[i];
    ushort4 o; o.x = f2bf(v.x); o.y = f2bf(v.y); o.z = f2bf(v.z); o.w = f2bf(v.w);
    reinterpret_cast<ushort4*>(out)[i] = o;
  }
}

// in: f32 [1024][1024] row-major -> out: bf16 [1024][1024] = in^T
__global__ __launch_bounds__(256) void transpose_w(const float* __restrict__ in,
                                                   u16* __restrict__ out) {
  __shared__ float tile[32][33];
  int bx = blockIdx.x, by = blockIdx.y;
  int x = threadIdx.x & 31, y0 = threadIdx.x >> 5;
#pragma unroll
  for (int i = 0; i < 4; i++) {
    int y = y0 + i * 8;
    tile[y][x] = in[(by * 32 + y) * NDM + bx * 32 + x];
  }
  __syncthreads();
#pragma unroll
  for (int i = 0; i < 4; i++) {
    int y = y0 + i * 8;
    out[(bx * 32 + y) * NDM + by * 32 + x] = f2bf(tile[x][y]);
  }
}

// ---- mask [B,S,S] -> bitmask, 1 bit/col ----
__global__ __launch_bounds__(256) void mask2bits(const u32* __restrict__ mask, u32* __restrict__ mb) {
  int idx = blockIdx.x * 256 + threadIdx.x;
  u32 mw0 = mask[threadIdx.x & 63];
  bool floatmode = (__ballot(mw0 == 0x3F800000u) != 0ull);
  bool bytemode = !floatmode && (__ballot((mw0 >> 8) != 0u) != 0ull);
  int row = idx >> 6;
  int wword = idx & 63;
  u32 bits = 0;
  if (!bytemode) {
    const uint4* p = reinterpret_cast<const uint4*>(mask + (size_t)row * 2048 + wword * 32);
#pragma unroll
    for (int i = 0; i < 8; i++) {
      uint4 v = p[i];
      bits |= (v.x ? 1u : 0u) << (i * 4 + 0);
      bits |= (v.y ? 1u : 0u) << (i * 4 + 1);
      bits |= (v.z ? 1u : 0u) << (i * 4 + 2);
      bits |= (v.w ? 1u : 0u) << (i * 4 + 3);
    }
  } else {
    const uint4* p = reinterpret_cast<const uint4*>(
        reinterpret_cast<const unsigned char*>(mask) + (size_t)row * 2048 + wword * 32);
#pragma unroll
    for (int i = 0; i < 2; i++) {
      uint4 v = p[i];
      u32 wsv[4] = {v.x, v.y, v.z, v.w};
#pragma unroll
      for (int j = 0; j < 4; j++)
#pragma unroll
        for (int kq = 0; kq < 4; kq++)
          bits |= ((((wsv[j] >> (kq * 8)) & 0xffu) != 0u) ? 1u : 0u) << (i * 16 + j * 4 + kq);
    }
  }
  mb[idx] = bits;
}

// ---- 128x128-tile bf16 GEMM, B^T layout ----
struct GArgs { const u16* X; const u16* W; const float* bias; void* out; int mode; float scale; };

__global__ __launch_bounds__(256, 2) void gemm_bt(GArgs g0, GArgs g1, GArgs g2) {
  GArgs ga = (blockIdx.z == 0) ? g0 : (blockIdx.z == 1 ? g1 : g2);
  const int K = 1024, N = 1024;
  __shared__ u16 As[128 * 32];
  __shared__ u16 Bs[128 * 32];
  const int t = threadIdx.x, w = t >> 6, l = t & 63;
  const int m0 = blockIdx.x * 128, n0 = blockIdx.y * 128;
  const int wm = (w >> 1) * 64, wn = (w & 1) * 64;
  const f32x4 fz = {0.f, 0.f, 0.f, 0.f};
  f32x4 acc[4][4];
#pragma unroll
  for (int i = 0; i < 4; i++)
#pragma unroll
    for (int j = 0; j < 4; j++) acc[i][j] = fz;

  for (int k0 = 0; k0 < K; k0 += 32) {
#pragma unroll
    for (int i = 0; i < 2; i++) {
      int idx = i * 256 + w * 64 + l;
      int r = idx >> 2, c = (idx & 3) * 8;
      __builtin_amdgcn_global_load_lds(
          reinterpret_cast<const unsigned*>(ga.X + (size_t)(m0 + r) * K + k0 + c),
          reinterpret_cast<unsigned*>(&As[(i * 256 + w * 64) * 8]), 16, 0, 0);
      __builtin_amdgcn_global_load_lds(
          reinterpret_cast<const unsigned*>(ga.W + (size_t)(n0 + r) * K + k0 + c),
          reinterpret_cast<unsigned*>(&Bs[(i * 256 + w * 64) * 8]), 16, 0, 0);
    }
    __syncthreads();
    bf16x8 af[4], bfr[4];
#pragma unroll
    for (int mt = 0; mt < 4; mt++)
      af[mt] = *reinterpret_cast<const bf16x8*>(&As[(wm + mt * 16 + (l & 15)) * 32 + (l >> 4) * 8]);
#pragma unroll
    for (int nt = 0; nt < 4; nt++)
      bfr[nt] = *reinterpret_cast<const bf16x8*>(&Bs[(wn + nt * 16 + (l & 15)) * 32 + (l >> 4) * 8]);
#pragma unroll
    for (int mt = 0; mt < 4; mt++)
#pragma unroll
      for (int nt = 0; nt < 4; nt++)
        acc[mt][nt] = __builtin_amdgcn_mfma_f32_16x16x32_bf16(af[mt], bfr[nt], acc[mt][nt], 0, 0, 0);
    __syncthreads();
  }

#pragma unroll
  for (int nt = 0; nt < 4; nt++) {
    int n = n0 + wn + nt * 16 + (l & 15);
    float bias = ga.bias[n];
#pragma unroll
    for (int mt = 0; mt < 4; mt++) {
      int mb = m0 + wm + mt * 16 + ((l >> 4) << 2);
#pragma unroll
      for (int r = 0; r < 4; r++) {
        int m = mb + r;
        float v = (acc[mt][nt][r] + bias) * ga.scale;
        if (ga.mode == 2) {
          reinterpret_cast<float*>(ga.out)[(size_t)m * N + n] = v;
        } else {
          int b = m >> 11, s = m & 2047, h = n >> 6, d = n & 63;
          if (ga.mode == 0)
            reinterpret_cast<u16*>(ga.out)[(((size_t)(b * NH + h) * NS + s) << 6) + d] = f2bf(v);
          else
            reinterpret_cast<u16*>(ga.out)[((size_t)(b * NH + h) * 64 + d) * NS + s] = f2bf(v);
        }
      }
    }
  }
}

// ---- attention: barrier-free, 3-buffer K prefetch (2 chunks ahead), full-line NT attn stores ----
__global__ __launch_bounds__(256, 3) void attn_kernel(
    const u16* __restrict__ qh, const u16* __restrict__ kh, const u16* __restrict__ vT,
    const u64* __restrict__ mb64, float* __restrict__ attn, u16* __restrict__ ctx) {
  __shared__ u16 Ps[4][16 * 72];      // per-wave bf16 P tile (PV A-frag relayout)
  __shared__ float Pf[4][16 * 68];    // per-wave f32 P tile (full-line attn stores)
  const int t = threadIdx.x, w = t >> 6, l = t & 63;
  int id = blockIdx.x;
  int wgid = (id & 7) * 128 + (id >> 3);   // XCD-chunked bijective swizzle (1024 % 8 == 0)
  int qt = wgid & 31, pr = wgid >> 5;
  int h = pr & 15, b = pr >> 4;
  const size_t head = (size_t)b * NH + h;
  const u16* qp = qh + head * NS * 64;
  const u16* kp = kh + head * NS * 64;
  const u16* vp = vT + head * 64 * NS;
  const int qr0 = qt * 64 + w * 16;
  const int lo = l & 15, hi = l >> 4;
  const int rbase = hi << 2;
  const f32x4 fz = {0.f, 0.f, 0.f, 0.f};

  bf16x8 aq0, aq1;
  {
    const u16* p = qp + (size_t)(qr0 + lo) * 64 + hi * 8;
    aq0 = *reinterpret_cast<const bf16x8*>(p);
    aq1 = *reinterpret_cast<const bf16x8*>(p + 32);
  }
  const u64* mrow = mb64 + ((size_t)b * NS + qr0 + rbase) * 32;

  auto loadK = [&](bf16x8* dst, int c) {
    const u16* kb = kp + (size_t)(c * 64) * 64;
#pragma unroll
    for (int ct = 0; ct < 4; ++ct) {
      const u16* p = kb + (size_t)(ct * 16 + lo) * 64 + hi * 8;
      dst[2 * ct] = *reinterpret_cast<const bf16x8*>(p);
      dst[2 * ct + 1] = *reinterpret_cast<const bf16x8*>(p + 32);
    }
  };
  auto qk = [&](const bf16x8* bk, f32x4* s) {
#pragma unroll
    for (int ct = 0; ct < 4; ++ct) {
      f32x4 acc = fz;
      acc = __builtin_amdgcn_mfma_f32_16x16x32_bf16(aq0, bk[2 * ct], acc, 0, 0, 0);
      acc = __builtin_amdgcn_mfma_f32_16x16x32_bf16(aq1, bk[2 * ct + 1], acc, 0, 0, 0);
      s[ct] = acc;
    }
  };

  // ---- pass 1: row sums only (q pre-scaled by 1/8 in projection) ----
  float rs[4] = {0.f, 0.f, 0.f, 0.f};
  {
    auto consume1 = [&](const bf16x8* bk, int cc) {
      u64 mwv[4] = {mrow[cc], mrow[32 + cc], mrow[64 + cc], mrow[96 + cc]};
      f32x4 s[4]; qk(bk, s);
#pragma unroll
      for (int ct = 0; ct < 4; ++ct) {
        int bit = ct * 16 + lo;
#pragma unroll
        for (int r = 0; r < 4; ++r)
          rs[r] += ((mwv[r] >> bit) & 1ull) ? 0.f : __expf(s[ct][r]);
      }
    };
    bf16x8 k0[8], k1[8], k2[8];
    loadK(k0, 0); loadK(k1, 1);
    for (int c = 0; c <= 27; c += 3) {          // modulo-3 rotated pipeline, 2 chunks ahead
      loadK(k2, c + 2); consume1(k0, c);
      loadK(k0, c + 3); consume1(k1, c + 1);
      loadK(k1, c + 4); consume1(k2, c + 2);
    }
    consume1(k0, 30); consume1(k1, 31);
  }
#pragma unroll
  for (int r = 0; r < 4; ++r) {
    float v = rs[r];
    v += __shfl_xor(v, 1); v += __shfl_xor(v, 2);
    v += __shfl_xor(v, 4); v += __shfl_xor(v, 8);
    rs[r] = 1.f / fmaxf(v, 1e-30f);
  }

  // ---- pass 2: recompute, full-line NT attn stores via Pf, PV ----
  f32x4 cacc[4];
#pragma unroll
  for (int i = 0; i < 4; i++) cacc[i] = fz;
  u16* psw = &Ps[w][0];
  float* pfw = &Pf[w][0];
  float* abase = attn + (head * NS + qr0) * NS;

  {
    auto consume2 = [&](const bf16x8* bk, int cc) {
      u64 mwv[4] = {mrow[cc], mrow[32 + cc], mrow[64 + cc], mrow[96 + cc]};
      f32x4 s[4]; qk(bk, s);
      // V fragments for this chunk (issued before the exp chain to hide latency)
      bf16x8 bv[8];
      {
        const u16* vb = vp + cc * 64;
#pragma unroll
        for (int ct = 0; ct < 4; ++ct) {
          const u16* p = vb + (size_t)(ct * 16 + lo) * NS + hi * 8;
          bv[2 * ct] = *reinterpret_cast<const bf16x8*>(p);
          bv[2 * ct + 1] = *reinterpret_cast<const bf16x8*>(p + 32);
        }
      }
#pragma unroll
      for (int ct = 0; ct < 4; ++ct) {
        int bit = ct * 16 + lo;
#pragma unroll
        for (int r = 0; r < 4; ++r) {
          float p = ((mwv[r] >> bit) & 1ull) ? 0.f : __expf(s[ct][r]) * rs[r];
          pfw[(rbase + r) * 68 + ct * 16 + lo] = p;
          psw[(rbase + r) * 72 + ct * 16 + lo] = f2bf(p);
        }
      }
      bf16x8 pa0 = *reinterpret_cast<const bf16x8*>(&psw[lo * 72 + hi * 8]);
      bf16x8 pa1 = *reinterpret_cast<const bf16x8*>(&psw[lo * 72 + 32 + hi * 8]);
#pragma unroll
      for (int ct = 0; ct < 4; ++ct) {
        cacc[ct] = __builtin_amdgcn_mfma_f32_16x16x32_bf16(pa0, bv[2 * ct], cacc[ct], 0, 0, 0);
        cacc[ct] = __builtin_amdgcn_mfma_f32_16x16x32_bf16(pa1, bv[2 * ct + 1], cacc[ct], 0, 0, 0);
      }
      // full-line (1KB/instr) nontemporal attn stores, after PV so they overlap the LDS wait
#pragma unroll
      for (int i2 = 0; i2 < 4; ++i2) {
        int row = i2 * 4 + hi;
        f32x4 pv4 = *reinterpret_cast<const f32x4*>(&pfw[row * 68 + lo * 4]);
        __builtin_nontemporal_store(pv4,
            reinterpret_cast<f32x4*>(abase + (size_t)row * NS + cc * 64 + lo * 4));
      }
    };
    bf16x8 k0[8], k1[8], k2[8];
    loadK(k0, 0); loadK(k1, 1);
    for (int c = 0; c <= 27; c += 3) {
      loadK(k2, c + 2); consume2(k0, c);
      loadK(k0, c + 3); consume2(k1, c + 1);
      loadK(k1, c + 4); consume2(k2, c + 2);
    }
    consume2(k0, 30); consume2(k1, 31);
  }
#pragma unroll
  for (int ct = 0; ct < 4; ++ct)
#pragma unroll
    for (int r = 0; r < 4; ++r) {
      int qr = qr0 + rbase + r;
      int dv = ct * 16 + lo;
      ctx[((size_t)b * NS + qr) * 1024 + h * 64 + dv] = f2bf(cacc[ct][r]);
    }
}

extern "C" void kernel_launch(void* const* d_in, const int* in_sizes, int n_in,
                              void* d_out, int out_size, void* d_ws, size_t ws_size,
                              hipStream_t stream) {
  const float* Q = (const float*)d_in[0];
  const float* K = (const float*)d_in[1];
  const float* V = (const float*)d_in[2];
  const u32* mask = (const u32*)d_in[3];
  const float* wq = (const float*)d_in[4];
  const float* bq = (const float*)d_in[5];
  const float* wk = (const float*)d_in[6];
  const float* bk = (const float*)d_in[7];
  const float* wv = (const float*)d_in[8];
  const float* bv = (const float*)d_in[9];
  const float* wo = (const float*)d_in[10];
  const float* bo = (const float*)d_in[11];
  float* out = (float*)d_out;
  float* attn = out + (size_t)NB * NS * NDM;

  char* ws = (char*)d_ws;
  u16* Qb  = (u16*)(ws + 0);
  u16* Kb  = (u16*)(ws + 8388608);
  u16* Vb  = (u16*)(ws + 16777216);
  u16* wqT = (u16*)(ws + 25165824);
  u16* wkT = (u16*)(ws + 27262976);
  u16* wvT = (u16*)(ws + 29360128);
  u16* woT = (u16*)(ws + 31457280);
  u16* qhd = (u16*)(ws + 33554432);
  u16* khd = (u16*)(ws + 41943040);
  u16* vTd = (u16*)(ws + 50331648);
  u16* ctx = (u16*)(ws + 58720256);
  u32* mbits = (u32*)(ws + 0);

  cast_bf16<<<4096, 256, 0, stream>>>(Q, Qb, 1048576);
  cast_bf16<<<4096, 256, 0, stream>>>(K, Kb, 1048576);
  cast_bf16<<<4096, 256, 0, stream>>>(V, Vb, 1048576);
  transpose_w<<<dim3(32, 32), 256, 0, stream>>>(wq, wqT);
  transpose_w<<<dim3(32, 32), 256, 0, stream>>>(wk, wkT);
  transpose_w<<<dim3(32, 32), 256, 0, stream>>>(wv, wvT);
  transpose_w<<<dim3(32, 32), 256, 0, stream>>>(wo, woT);

  GArgs gq = {Qb, wqT, bq, (void*)qhd, 0, 0.125f};   // fold 1/sqrt(dk) into q
  GArgs gk = {Kb, wkT, bk, (void*)khd, 0, 1.0f};
  GArgs gv = {Vb, wvT, bv, (void*)vTd, 1, 1.0f};
  gemm_bt<<<dim3(32, 8, 3), 256, 0, stream>>>(gq, gk, gv);

  mask2bits<<<1024, 256, 0, stream>>>(mask, mbits);

  attn_kernel<<<1024, 256, 0, stream>>>(qhd, khd, vTd, (const u64*)mbits, attn, ctx);

  GArgs go = {ctx, woT, bo, d_out, 2, 1.0f};
  gemm_bt<<<dim3(32, 8, 1), 256, 0, stream>>>(go, go, go);
}